// Round 1
// baseline (1561.620 us; speedup 1.0000x reference)
//
#include <hip/hip_runtime.h>
#include <math.h>

#define NGRID 32768   // 32^3 latent grid points
#define NOUT  16384   // output queries
#define CCH   256     // latent channels
#define H1DIM 512     // hidden width layer 1
#define TE    16      // edges per block

__device__ __forceinline__ float gelu_exact(float x) {
    return 0.5f * x * (1.0f + erff(x * 0.70710678118654752f));
}

__global__ __launch_bounds__(256) void gino_edge_kernel(
    const float* __restrict__ latent_embed,   // (2, 32768, 256)
    const float* __restrict__ latent_queries, // (32768, 3)
    const float* __restrict__ output_queries, // (16384, 3)
    const int*   __restrict__ nb_index,       // (E)
    const int*   __restrict__ out_index,      // (E)
    const float* __restrict__ W1, const float* __restrict__ b1, // (6,512),(512)
    const float* __restrict__ W2, const float* __restrict__ b2, // (512,256),(256)
    const float* __restrict__ W3, const float* __restrict__ b3, // (256,256),(256)
    const float* __restrict__ Wp,                               // (256,4)
    float* __restrict__ sums,   // (2, 16384, 4) accumulators
    float* __restrict__ cnt,    // (16384)
    int E)
{
    __shared__ float s_agg[TE][8];
    __shared__ float s_h1[TE][H1DIM];
    __shared__ float s_h2[TE][CCH];   // reused to hold k after layer 3
    __shared__ int   s_nb[TE];
    __shared__ int   s_oi[TE];
    __shared__ int   s_valid[TE];

    const int tid = threadIdx.x;
    const int e0  = blockIdx.x * TE;

    // ---- Phase 0: load indices + coords for this edge tile ----
    if (tid < TE) {
        int e     = e0 + tid;
        int valid = (e < E) ? 1 : 0;
        int ec    = valid ? e : (E - 1);   // clamp for safe (garbage) loads
        int nb    = nb_index[ec];
        int oi    = out_index[ec];
        s_nb[tid]    = nb;
        s_oi[tid]    = oi;
        s_valid[tid] = valid;
        s_agg[tid][0] = latent_queries[nb * 3 + 0];
        s_agg[tid][1] = latent_queries[nb * 3 + 1];
        s_agg[tid][2] = latent_queries[nb * 3 + 2];
        s_agg[tid][3] = output_queries[oi * 3 + 0];
        s_agg[tid][4] = output_queries[oi * 3 + 1];
        s_agg[tid][5] = output_queries[oi * 3 + 2];
        if (valid) atomicAdd(&cnt[oi], 1.0f);
    }
    __syncthreads();

    // ---- Phase 1: layer 1  h1 = gelu(agg @ W1 + b1)   (TE x 512) ----
    for (int idx = tid; idx < TE * H1DIM; idx += 256) {
        int e = idx >> 9;        // /512
        int j = idx & (H1DIM-1); // %512
        float v = b1[j];
        #pragma unroll
        for (int i = 0; i < 6; ++i) v = fmaf(s_agg[e][i], W1[i * H1DIM + j], v);
        s_h1[e][j] = gelu_exact(v);
    }
    __syncthreads();

    // ---- Phase 2: layer 2  h2 = gelu(h1 @ W2 + b2)  (TE x 256) ----
    {
        const int j = tid;  // output column
        float acc[TE];
        #pragma unroll
        for (int e = 0; e < TE; ++e) acc[e] = 0.0f;
        for (int i = 0; i < H1DIM; i += 4) {
            float w0 = W2[(i + 0) * CCH + j];
            float w1 = W2[(i + 1) * CCH + j];
            float w2 = W2[(i + 2) * CCH + j];
            float w3 = W2[(i + 3) * CCH + j];
            #pragma unroll
            for (int e = 0; e < TE; ++e) {
                float4 h = *(const float4*)&s_h1[e][i];  // broadcast LDS read
                acc[e] = fmaf(h.x, w0, fmaf(h.y, w1, fmaf(h.z, w2, fmaf(h.w, w3, acc[e]))));
            }
        }
        float bb = b2[j];
        #pragma unroll
        for (int e = 0; e < TE; ++e) s_h2[e][j] = gelu_exact(acc[e] + bb);
    }
    __syncthreads();

    // ---- Phase 3: layer 3  k = h2 @ W3 + b3   (TE x 256), write back over s_h2 ----
    {
        const int j = tid;
        float acc[TE];
        #pragma unroll
        for (int e = 0; e < TE; ++e) acc[e] = 0.0f;
        for (int i = 0; i < CCH; i += 4) {
            float w0 = W3[(i + 0) * CCH + j];
            float w1 = W3[(i + 1) * CCH + j];
            float w2 = W3[(i + 2) * CCH + j];
            float w3 = W3[(i + 3) * CCH + j];
            #pragma unroll
            for (int e = 0; e < TE; ++e) {
                float4 h = *(const float4*)&s_h2[e][i];  // broadcast LDS read
                acc[e] = fmaf(h.x, w0, fmaf(h.y, w1, fmaf(h.z, w2, fmaf(h.w, w3, acc[e]))));
            }
        }
        __syncthreads();  // all reads of h2 done before overwrite
        float bb = b3[j];
        #pragma unroll
        for (int e = 0; e < TE; ++e) s_h2[e][j] = acc[e] + bb;
    }
    __syncthreads();

    // ---- Phase 4: per-edge  pm[oc] = sum_c k[c]*f[b,nb,c]*Wp[c,oc]; atomic accumulate ----
    {
        const int wave = tid >> 6;
        const int lane = tid & 63;
        // this lane owns channels c = lane*4 .. lane*4+3
        float4 wp0 = *(const float4*)&Wp[(lane * 4 + 0) * 4];
        float4 wp1 = *(const float4*)&Wp[(lane * 4 + 1) * 4];
        float4 wp2 = *(const float4*)&Wp[(lane * 4 + 2) * 4];
        float4 wp3 = *(const float4*)&Wp[(lane * 4 + 3) * 4];

        for (int el = wave; el < TE; el += 4) {
            if (!s_valid[el]) continue;
            int nb = s_nb[el];
            int oi = s_oi[el];
            float4 k4 = *(const float4*)&s_h2[el][lane * 4];
            #pragma unroll
            for (int b = 0; b < 2; ++b) {
                const float* fptr = latent_embed + ((size_t)b * NGRID + nb) * CCH + lane * 4;
                float4 f4 = *(const float4*)fptr;
                float t0 = k4.x * f4.x;
                float t1 = k4.y * f4.y;
                float t2 = k4.z * f4.z;
                float t3 = k4.w * f4.w;
                float pm0 = t0 * wp0.x + t1 * wp1.x + t2 * wp2.x + t3 * wp3.x;
                float pm1 = t0 * wp0.y + t1 * wp1.y + t2 * wp2.y + t3 * wp3.y;
                float pm2 = t0 * wp0.z + t1 * wp1.z + t2 * wp2.z + t3 * wp3.z;
                float pm3 = t0 * wp0.w + t1 * wp1.w + t2 * wp2.w + t3 * wp3.w;
                #pragma unroll
                for (int off = 32; off > 0; off >>= 1) {
                    pm0 += __shfl_down(pm0, off);
                    pm1 += __shfl_down(pm1, off);
                    pm2 += __shfl_down(pm2, off);
                    pm3 += __shfl_down(pm3, off);
                }
                if (lane == 0) {
                    float* sp = sums + ((size_t)b * NOUT + oi) * 4;
                    atomicAdd(sp + 0, pm0);
                    atomicAdd(sp + 1, pm1);
                    atomicAdd(sp + 2, pm2);
                    atomicAdd(sp + 3, pm3);
                }
            }
        }
    }
}

__global__ __launch_bounds__(256) void gino_finalize_kernel(
    const float* __restrict__ sums,
    const float* __restrict__ cnt,
    const float* __restrict__ bp,
    float* __restrict__ out)
{
    int idx = blockIdx.x * 256 + threadIdx.x;
    if (idx >= 2 * NOUT * 4) return;
    int oc = idx & 3;
    int i  = (idx >> 2) & (NOUT - 1);
    float c = fmaxf(cnt[i], 1.0f);
    out[idx] = sums[idx] / c + bp[oc];
}

extern "C" void kernel_launch(void* const* d_in, const int* in_sizes, int n_in,
                              void* d_out, int out_size, void* d_ws, size_t ws_size,
                              hipStream_t stream) {
    const float* latent_embed   = (const float*)d_in[0];
    const float* latent_queries = (const float*)d_in[1];
    const float* output_queries = (const float*)d_in[2];
    const int*   nb_index       = (const int*)d_in[3];
    const int*   out_index      = (const int*)d_in[4];
    const float* W1 = (const float*)d_in[5];
    const float* b1 = (const float*)d_in[6];
    const float* W2 = (const float*)d_in[7];
    const float* b2 = (const float*)d_in[8];
    const float* W3 = (const float*)d_in[9];
    const float* b3 = (const float*)d_in[10];
    const float* Wp = (const float*)d_in[11];
    const float* bp = (const float*)d_in[12];

    const int E = in_sizes[3];

    float* sums = (float*)d_ws;                 // 2*16384*4 floats
    float* cnt  = sums + 2 * NOUT * 4;          // 16384 floats
    hipMemsetAsync(d_ws, 0, (size_t)(2 * NOUT * 4 + NOUT) * sizeof(float), stream);

    int nblk = (E + TE - 1) / TE;
    gino_edge_kernel<<<nblk, 256, 0, stream>>>(
        latent_embed, latent_queries, output_queries, nb_index, out_index,
        W1, b1, W2, b2, W3, b3, Wp, sums, cnt, E);

    gino_finalize_kernel<<<(2 * NOUT * 4 + 255) / 256, 256, 0, stream>>>(
        sums, cnt, bp, (float*)d_out);
}

// Round 2
// 361.700 us; speedup vs baseline: 4.3174x; 4.3174x over previous
//
#include <hip/hip_runtime.h>
#include <math.h>

#define NGRID 32768   // 32^3 latent grid points
#define NOUT  16384   // output queries
#define CCH   256     // latent channels
#define H1DIM 512     // hidden width layer 1
#define TE    32      // edges per block

typedef _Float16 f16x8 __attribute__((ext_vector_type(8)));
typedef float    f32x16 __attribute__((ext_vector_type(16)));

__device__ __forceinline__ unsigned short f32_to_f16_bits(float v) {
    _Float16 h = (_Float16)v;
    return __builtin_bit_cast(unsigned short, h);
}

// gelu(x) = 0.5 x (1 + erf(x/sqrt2)), erf via Abramowitz-Stegun 7.1.26 (|err|<1.5e-7)
__device__ __forceinline__ float gelu_fast(float x) {
    float ax = fabsf(x) * 0.70710678118654752f;
    float t  = __builtin_amdgcn_rcpf(fmaf(0.3275911f, ax, 1.0f));
    float p  = fmaf(fmaf(fmaf(fmaf(1.061405429f, t, -1.453152027f), t, 1.421413741f), t,
                         -0.284496736f), t, 0.254829592f) * t;
    float e  = __expf(-ax * ax);
    float er = fmaf(-p, e, 1.0f);
    er = (x >= 0.0f) ? er : -er;
    return 0.5f * x * (1.0f + er);
}

// Pack W2 (512x256) and W3 (256x256) into 32x32x16 A-fragment order, f16.
// A[m=ch][k], frag lane l: m = l&31, k = ks*16 + (l>>5)*8 + j.
// Flat: [ks][g(8)][lane(64)][j(8)] ; ch = g*32 + (l&31).
__global__ __launch_bounds__(256) void gino_pack_kernel(
    const float* __restrict__ W2, const float* __restrict__ W3,
    unsigned short* __restrict__ W2F, unsigned short* __restrict__ W3F)
{
    int idx = blockIdx.x * 256 + threadIdx.x;
    if (idx < 32 * 8 * 64) {          // W2F: ks 0..31
        int l = idx & 63, g = (idx >> 6) & 7, ks = idx >> 9;
        int ch = g * 32 + (l & 31);
        int k0 = ks * 16 + (l >> 5) * 8;
        unsigned int u[4];
        #pragma unroll
        for (int p = 0; p < 4; ++p) {
            unsigned int lo = f32_to_f16_bits(W2[(k0 + 2 * p) * CCH + ch]);
            unsigned int hh = f32_to_f16_bits(W2[(k0 + 2 * p + 1) * CCH + ch]);
            u[p] = lo | (hh << 16);
        }
        *(uint4*)(W2F + idx * 8) = make_uint4(u[0], u[1], u[2], u[3]);
    } else if (idx < 32 * 8 * 64 + 16 * 8 * 64) {   // W3F: ks 0..15
        int i2 = idx - 32 * 8 * 64;
        int l = i2 & 63, g = (i2 >> 6) & 7, ks = i2 >> 9;
        int ch = g * 32 + (l & 31);
        int k0 = ks * 16 + (l >> 5) * 8;
        unsigned int u[4];
        #pragma unroll
        for (int p = 0; p < 4; ++p) {
            unsigned int lo = f32_to_f16_bits(W3[(k0 + 2 * p) * CCH + ch]);
            unsigned int hh = f32_to_f16_bits(W3[(k0 + 2 * p + 1) * CCH + ch]);
            u[p] = lo | (hh << 16);
        }
        *(uint4*)(W3F + i2 * 8) = make_uint4(u[0], u[1], u[2], u[3]);
    }
}

__global__ __launch_bounds__(256) void gino_edge_kernel(
    const float* __restrict__ latent_embed,   // (2, 32768, 256)
    const float* __restrict__ latent_queries, // (32768, 3)
    const float* __restrict__ output_queries, // (16384, 3)
    const int*   __restrict__ nb_index,
    const int*   __restrict__ out_index,
    const float* __restrict__ W1, const float* __restrict__ b1,
    const float* __restrict__ b2, const float* __restrict__ b3,
    const unsigned short* __restrict__ W2F,
    const unsigned short* __restrict__ W3F,
    const float* __restrict__ Wp,
    float* __restrict__ sums, float* __restrict__ cnt, int E)
{
    // s_h1k: h1 as f16 swizzled [32][512] (32KB), later reused for k fp32 [32][256] (32KB)
    __shared__ __align__(16) unsigned char s_h1k[TE * 1024];
    __shared__ __align__(16) unsigned char s_h2[TE * 512];   // h2 f16 swizzled [32][256]
    __shared__ float s_agg[TE][8];
    __shared__ int s_nb[TE], s_oi[TE], s_valid[TE];

    const int tid = threadIdx.x;
    const int e0  = blockIdx.x * TE;

    // ---- Phase 0: indices + coords ----
    if (tid < TE) {
        int e     = e0 + tid;
        int valid = (e < E) ? 1 : 0;
        int ec    = valid ? e : (E - 1);
        int nb    = nb_index[ec];
        int oi    = out_index[ec];
        s_nb[tid] = nb; s_oi[tid] = oi; s_valid[tid] = valid;
        s_agg[tid][0] = latent_queries[nb * 3 + 0];
        s_agg[tid][1] = latent_queries[nb * 3 + 1];
        s_agg[tid][2] = latent_queries[nb * 3 + 2];
        s_agg[tid][3] = output_queries[oi * 3 + 0];
        s_agg[tid][4] = output_queries[oi * 3 + 1];
        s_agg[tid][5] = output_queries[oi * 3 + 2];
        if (valid) atomicAdd(&cnt[oi], 1.0f);
    }
    __syncthreads();

    const int l  = tid & 63;
    const int w  = tid >> 6;      // wave id 0..3
    const int le = l & 31;
    const int hi = l >> 5;
    const unsigned int swz = (unsigned int)(le & 7) << 4;

    // ---- Phase 1: h1 = gelu(agg @ W1 + b1) -> f16 LDS, swizzled ----
    {
        const int k0 = l * 8;     // lane owns k-chunk, wave w owns edges 8w..8w+7
        float w1r[6][8];
        #pragma unroll
        for (int i = 0; i < 6; ++i) {
            *(float4*)&w1r[i][0] = *(const float4*)(W1 + i * H1DIM + k0);
            *(float4*)&w1r[i][4] = *(const float4*)(W1 + i * H1DIM + k0 + 4);
        }
        float b1r[8];
        *(float4*)&b1r[0] = *(const float4*)(b1 + k0);
        *(float4*)&b1r[4] = *(const float4*)(b1 + k0 + 4);
        #pragma unroll
        for (int ee = 0; ee < 8; ++ee) {
            int e = w * 8 + ee;
            float a0 = s_agg[e][0], a1 = s_agg[e][1], a2 = s_agg[e][2];
            float a3 = s_agg[e][3], a4 = s_agg[e][4], a5 = s_agg[e][5];
            unsigned int u[4];
            #pragma unroll
            for (int p = 0; p < 4; ++p) {
                unsigned int uu[2];
                #pragma unroll
                for (int q = 0; q < 2; ++q) {
                    int j = 2 * p + q;
                    float v = b1r[j];
                    v = fmaf(a0, w1r[0][j], v);
                    v = fmaf(a1, w1r[1][j], v);
                    v = fmaf(a2, w1r[2][j], v);
                    v = fmaf(a3, w1r[3][j], v);
                    v = fmaf(a4, w1r[4][j], v);
                    v = fmaf(a5, w1r[5][j], v);
                    uu[q] = f32_to_f16_bits(gelu_fast(v));
                }
                u[p] = uu[0] | (uu[1] << 16);
            }
            *(uint4*)(s_h1k + e * 1024 + (((unsigned)k0 * 2) ^ (((unsigned)(e & 7)) << 4))) =
                make_uint4(u[0], u[1], u[2], u[3]);
        }
    }
    __syncthreads();

    // ---- Phase 2: h2 = gelu(h1 @ W2 + b2) via MFMA (A=W2 frags, B=h1) ----
    f32x16 acc0 = {}, acc1 = {};
    {
        const unsigned short* pa = W2F + w * 2 * 512 + l * 8;
        #pragma unroll
        for (int ks = 0; ks < 32; ++ks) {
            f16x8 bfr = *(const f16x8*)(s_h1k + le * 1024 +
                          (((unsigned)(ks * 32 + hi * 16)) ^ swz));
            f16x8 a0 = *(const f16x8*)(pa + ks * 4096);
            f16x8 a1 = *(const f16x8*)(pa + ks * 4096 + 512);
            acc0 = __builtin_amdgcn_mfma_f32_32x32x16_f16(a0, bfr, acc0, 0, 0, 0);
            acc1 = __builtin_amdgcn_mfma_f32_32x32x16_f16(a1, bfr, acc1, 0, 0, 0);
        }
    }
    // epilogue: D[ch][e]: col=l&31 (edge), row=(reg&3)+8*(reg>>2)+4*hi (ch-local)
    #pragma unroll
    for (int t2 = 0; t2 < 2; ++t2) {
        int g = w * 2 + t2;
        #pragma unroll
        for (int q = 0; q < 4; ++q) {
            int ch0 = g * 32 + q * 8 + hi * 4;
            float4 bb = *(const float4*)(b2 + ch0);
            float v0 = (t2 ? acc1[q * 4 + 0] : acc0[q * 4 + 0]) + bb.x;
            float v1 = (t2 ? acc1[q * 4 + 1] : acc0[q * 4 + 1]) + bb.y;
            float v2 = (t2 ? acc1[q * 4 + 2] : acc0[q * 4 + 2]) + bb.z;
            float v3 = (t2 ? acc1[q * 4 + 3] : acc0[q * 4 + 3]) + bb.w;
            unsigned int u0 = f32_to_f16_bits(gelu_fast(v0)) |
                              ((unsigned)f32_to_f16_bits(gelu_fast(v1)) << 16);
            unsigned int u1 = f32_to_f16_bits(gelu_fast(v2)) |
                              ((unsigned)f32_to_f16_bits(gelu_fast(v3)) << 16);
            *(uint2*)(s_h2 + le * 512 + (((unsigned)(ch0 * 2)) ^ swz)) = make_uint2(u0, u1);
        }
    }
    __syncthreads();

    // ---- Phase 3: k = h2 @ W3 + b3 via MFMA; write fp32 k into s_h1k region ----
    f32x16 kc0 = {}, kc1 = {};
    {
        const unsigned short* pa = W3F + w * 2 * 512 + l * 8;
        #pragma unroll
        for (int ks = 0; ks < 16; ++ks) {
            f16x8 bfr = *(const f16x8*)(s_h2 + le * 512 +
                          (((unsigned)(ks * 32 + hi * 16)) ^ swz));
            f16x8 a0 = *(const f16x8*)(pa + ks * 4096);
            f16x8 a1 = *(const f16x8*)(pa + ks * 4096 + 512);
            kc0 = __builtin_amdgcn_mfma_f32_32x32x16_f16(a0, bfr, kc0, 0, 0, 0);
            kc1 = __builtin_amdgcn_mfma_f32_32x32x16_f16(a1, bfr, kc1, 0, 0, 0);
        }
    }
    #pragma unroll
    for (int t2 = 0; t2 < 2; ++t2) {
        int g = w * 2 + t2;
        #pragma unroll
        for (int q = 0; q < 4; ++q) {
            int ch0 = g * 32 + q * 8 + hi * 4;
            float4 bb = *(const float4*)(b3 + ch0);
            float4 kv;
            kv.x = (t2 ? kc1[q * 4 + 0] : kc0[q * 4 + 0]) + bb.x;
            kv.y = (t2 ? kc1[q * 4 + 1] : kc0[q * 4 + 1]) + bb.y;
            kv.z = (t2 ? kc1[q * 4 + 2] : kc0[q * 4 + 2]) + bb.z;
            kv.w = (t2 ? kc1[q * 4 + 3] : kc0[q * 4 + 3]) + bb.w;
            *(float4*)(s_h1k + le * 1024 + (((unsigned)(ch0 * 4)) ^ swz)) = kv;
        }
    }
    __syncthreads();

    // ---- Phase 4: pm[oc] = sum_c k[c]*f[b,nb,c]*Wp[c,oc]; shuffle-reduce + atomic ----
    {
        float4 wp0 = *(const float4*)&Wp[(l * 4 + 0) * 4];
        float4 wp1 = *(const float4*)&Wp[(l * 4 + 1) * 4];
        float4 wp2 = *(const float4*)&Wp[(l * 4 + 2) * 4];
        float4 wp3 = *(const float4*)&Wp[(l * 4 + 3) * 4];

        for (int el = w; el < TE; el += 4) {
            if (!s_valid[el]) continue;
            int nb = s_nb[el];
            int oi = s_oi[el];
            float4 k4 = *(const float4*)(s_h1k + el * 1024 +
                          (((unsigned)(l * 16)) ^ (((unsigned)(el & 7)) << 4)));
            #pragma unroll
            for (int b = 0; b < 2; ++b) {
                const float* fptr = latent_embed + ((size_t)b * NGRID + nb) * CCH + l * 4;
                float4 f4 = *(const float4*)fptr;
                float t0 = k4.x * f4.x;
                float t1 = k4.y * f4.y;
                float t2 = k4.z * f4.z;
                float t3 = k4.w * f4.w;
                float pm0 = t0 * wp0.x + t1 * wp1.x + t2 * wp2.x + t3 * wp3.x;
                float pm1 = t0 * wp0.y + t1 * wp1.y + t2 * wp2.y + t3 * wp3.y;
                float pm2 = t0 * wp0.z + t1 * wp1.z + t2 * wp2.z + t3 * wp3.z;
                float pm3 = t0 * wp0.w + t1 * wp1.w + t2 * wp2.w + t3 * wp3.w;
                #pragma unroll
                for (int off = 32; off > 0; off >>= 1) {
                    pm0 += __shfl_down(pm0, off);
                    pm1 += __shfl_down(pm1, off);
                    pm2 += __shfl_down(pm2, off);
                    pm3 += __shfl_down(pm3, off);
                }
                if (l == 0) {
                    float* sp = sums + ((size_t)b * NOUT + oi) * 4;
                    atomicAdd(sp + 0, pm0);
                    atomicAdd(sp + 1, pm1);
                    atomicAdd(sp + 2, pm2);
                    atomicAdd(sp + 3, pm3);
                }
            }
        }
    }
}

__global__ __launch_bounds__(256) void gino_finalize_kernel(
    const float* __restrict__ sums,
    const float* __restrict__ cnt,
    const float* __restrict__ bp,
    float* __restrict__ out)
{
    int idx = blockIdx.x * 256 + threadIdx.x;
    if (idx >= 2 * NOUT * 4) return;
    int oc = idx & 3;
    int i  = (idx >> 2) & (NOUT - 1);
    float c = fmaxf(cnt[i], 1.0f);
    out[idx] = sums[idx] / c + bp[oc];
}

extern "C" void kernel_launch(void* const* d_in, const int* in_sizes, int n_in,
                              void* d_out, int out_size, void* d_ws, size_t ws_size,
                              hipStream_t stream) {
    const float* latent_embed   = (const float*)d_in[0];
    const float* latent_queries = (const float*)d_in[1];
    const float* output_queries = (const float*)d_in[2];
    const int*   nb_index       = (const int*)d_in[3];
    const int*   out_index      = (const int*)d_in[4];
    const float* W1 = (const float*)d_in[5];
    const float* b1 = (const float*)d_in[6];
    const float* W2 = (const float*)d_in[7];
    const float* b2 = (const float*)d_in[8];
    const float* W3 = (const float*)d_in[9];
    const float* b3 = (const float*)d_in[10];
    const float* Wp = (const float*)d_in[11];
    const float* bp = (const float*)d_in[12];

    const int E = in_sizes[3];

    float* sums = (float*)d_ws;                         // 2*16384*4 fp32  (512KB)
    float* cnt  = sums + 2 * NOUT * 4;                  // 16384 fp32      (64KB)
    unsigned short* W2F = (unsigned short*)(cnt + NOUT);// 32*8*64*8 f16   (256KB)
    unsigned short* W3F = W2F + 32 * 8 * 64 * 8;        // 16*8*64*8 f16   (128KB)

    hipMemsetAsync(d_ws, 0, (size_t)(2 * NOUT * 4 + NOUT) * sizeof(float), stream);

    gino_pack_kernel<<<(32 * 8 * 64 + 16 * 8 * 64 + 255) / 256, 256, 0, stream>>>(
        W2, W3, W2F, W3F);

    int nblk = (E + TE - 1) / TE;
    gino_edge_kernel<<<nblk, 256, 0, stream>>>(
        latent_embed, latent_queries, output_queries, nb_index, out_index,
        W1, b1, b2, b3, W2F, W3F, Wp, sums, cnt, E);

    gino_finalize_kernel<<<(2 * NOUT * 4 + 255) / 256, 256, 0, stream>>>(
        sums, cnt, bp, (float*)d_out);
}

// Round 3
// 291.337 us; speedup vs baseline: 5.3602x; 1.2415x over previous
//
#include <hip/hip_runtime.h>
#include <math.h>

#define NGRID 32768   // 32^3 latent grid points
#define NOUT  16384   // output queries
#define CCH   256     // latent channels
#define H1DIM 512     // hidden width layer 1
#define TE    32      // edges per block

typedef _Float16 f16x8 __attribute__((ext_vector_type(8)));
typedef float    f32x16 __attribute__((ext_vector_type(16)));

__device__ __forceinline__ unsigned short f32_to_f16_bits(float v) {
    _Float16 h = (_Float16)v;
    return __builtin_bit_cast(unsigned short, h);
}

// swizzle: row r -> XOR of byte-offset bits 4..6; aligned lane-quads hit distinct slots
__device__ __forceinline__ unsigned swz_row(int r) {
    return (unsigned)(((r & 7) ^ ((r >> 3) & 3)) << 4);
}

// gelu(x) = 0.5 x (1 + erf(x/sqrt2)), erf via Abramowitz-Stegun 7.1.26 (|err|<1.5e-7)
__device__ __forceinline__ float gelu_fast(float x) {
    float ax = fabsf(x) * 0.70710678118654752f;
    float t  = __builtin_amdgcn_rcpf(fmaf(0.3275911f, ax, 1.0f));
    float p  = fmaf(fmaf(fmaf(fmaf(1.061405429f, t, -1.453152027f), t, 1.421413741f), t,
                         -0.284496736f), t, 0.254829592f) * t;
    float e  = __expf(-ax * ax);
    float er = fmaf(-p, e, 1.0f);
    er = (x >= 0.0f) ? er : -er;
    return 0.5f * x * (1.0f + er);
}

// Pack W2 (512x256) and W3 (256x256) into 32x32x16 A-fragment order, f16.
// A[m=ch][k], frag lane l: m = l&31, k = ks*16 + (l>>5)*8 + j.
// Flat: [ks][g(8)][lane(64)][j(8)] ; ch = g*32 + (l&31).
__global__ __launch_bounds__(256) void gino_pack_kernel(
    const float* __restrict__ W2, const float* __restrict__ W3,
    unsigned short* __restrict__ W2F, unsigned short* __restrict__ W3F)
{
    int idx = blockIdx.x * 256 + threadIdx.x;
    if (idx < 32 * 8 * 64) {          // W2F: ks 0..31
        int l = idx & 63, g = (idx >> 6) & 7, ks = idx >> 9;
        int ch = g * 32 + (l & 31);
        int k0 = ks * 16 + (l >> 5) * 8;
        unsigned int u[4];
        #pragma unroll
        for (int p = 0; p < 4; ++p) {
            unsigned int lo = f32_to_f16_bits(W2[(k0 + 2 * p) * CCH + ch]);
            unsigned int hh = f32_to_f16_bits(W2[(k0 + 2 * p + 1) * CCH + ch]);
            u[p] = lo | (hh << 16);
        }
        *(uint4*)(W2F + idx * 8) = make_uint4(u[0], u[1], u[2], u[3]);
    } else if (idx < 32 * 8 * 64 + 16 * 8 * 64) {   // W3F: ks 0..15
        int i2 = idx - 32 * 8 * 64;
        int l = i2 & 63, g = (i2 >> 6) & 7, ks = i2 >> 9;
        int ch = g * 32 + (l & 31);
        int k0 = ks * 16 + (l >> 5) * 8;
        unsigned int u[4];
        #pragma unroll
        for (int p = 0; p < 4; ++p) {
            unsigned int lo = f32_to_f16_bits(W3[(k0 + 2 * p) * CCH + ch]);
            unsigned int hh = f32_to_f16_bits(W3[(k0 + 2 * p + 1) * CCH + ch]);
            u[p] = lo | (hh << 16);
        }
        *(uint4*)(W3F + i2 * 8) = make_uint4(u[0], u[1], u[2], u[3]);
    }
}

__global__ __launch_bounds__(256, 4) void gino_edge_kernel(
    const float* __restrict__ latent_embed,   // (2, 32768, 256)
    const float* __restrict__ latent_queries, // (32768, 3)
    const float* __restrict__ output_queries, // (16384, 3)
    const int*   __restrict__ nb_index,
    const int*   __restrict__ out_index,
    const float* __restrict__ W1, const float* __restrict__ b1,
    const float* __restrict__ b2, const float* __restrict__ b3,
    const unsigned short* __restrict__ W2F,
    const unsigned short* __restrict__ W3F,
    const float* __restrict__ Wp,
    float* __restrict__ sums, float* __restrict__ cnt, int E)
{
    __shared__ __align__(16) unsigned char s_h1[TE * 512];  // h1 half-chunk f16 swz [32][256]
    __shared__ __align__(16) unsigned char s_h2[TE * 512];  // h2 f16 swizzled [32][256]
    __shared__ float s_agg[TE][8];
    __shared__ float s_pm[TE][8];
    __shared__ int s_nb[TE], s_oi[TE], s_valid[TE];

    const int tid = threadIdx.x;
    const int e0  = blockIdx.x * TE;

    // ---- Phase 0: indices + coords, zero s_pm ----
    ((float*)s_pm)[tid] = 0.0f;
    if (tid < TE) {
        int e     = e0 + tid;
        int valid = (e < E) ? 1 : 0;
        int ec    = valid ? e : (E - 1);
        int nb    = nb_index[ec];
        int oi    = out_index[ec];
        s_nb[tid] = nb; s_oi[tid] = oi; s_valid[tid] = valid;
        s_agg[tid][0] = latent_queries[nb * 3 + 0];
        s_agg[tid][1] = latent_queries[nb * 3 + 1];
        s_agg[tid][2] = latent_queries[nb * 3 + 2];
        s_agg[tid][3] = output_queries[oi * 3 + 0];
        s_agg[tid][4] = output_queries[oi * 3 + 1];
        s_agg[tid][5] = output_queries[oi * 3 + 2];
        if (valid) atomicAdd(&cnt[oi], 1.0f);
    }
    __syncthreads();

    const int l  = tid & 63;
    const int w  = tid >> 6;      // wave id 0..3
    const int le = l & 31;
    const int hi = l >> 5;
    const unsigned swz = swz_row(le);

    f32x16 acc0 = {}, acc1 = {};   // h2 accumulators (held across both K-chunks)

    // ---- Phases 1/2 interleaved over two K-chunks of h1 ----
    #pragma unroll
    for (int chunk = 0; chunk < 2; ++chunk) {
        // Phase 1: h1 chunk = gelu(agg @ W1[:, chunk*256 ...] + b1) -> f16 LDS, swizzled
        {
            const int kc = chunk * 256 + l * 4;   // lane owns 4 cols; wave w owns edges 8w..8w+7
            float w1r[6][4];
            #pragma unroll
            for (int i = 0; i < 6; ++i)
                *(float4*)&w1r[i][0] = *(const float4*)(W1 + i * H1DIM + kc);
            float4 b1r = *(const float4*)(b1 + kc);
            #pragma unroll
            for (int ee = 0; ee < 8; ++ee) {
                int e = w * 8 + ee;
                float a0 = s_agg[e][0], a1 = s_agg[e][1], a2 = s_agg[e][2];
                float a3 = s_agg[e][3], a4 = s_agg[e][4], a5 = s_agg[e][5];
                unsigned int u[2];
                #pragma unroll
                for (int p = 0; p < 2; ++p) {
                    unsigned int uu[2];
                    #pragma unroll
                    for (int q = 0; q < 2; ++q) {
                        int j = 2 * p + q;
                        float v = (j == 0) ? b1r.x : (j == 1) ? b1r.y : (j == 2) ? b1r.z : b1r.w;
                        v = fmaf(a0, w1r[0][j], v);
                        v = fmaf(a1, w1r[1][j], v);
                        v = fmaf(a2, w1r[2][j], v);
                        v = fmaf(a3, w1r[3][j], v);
                        v = fmaf(a4, w1r[4][j], v);
                        v = fmaf(a5, w1r[5][j], v);
                        uu[q] = f32_to_f16_bits(gelu_fast(v));
                    }
                    u[p] = uu[0] | (uu[1] << 16);
                }
                *(uint2*)(s_h1 + e * 512 + (((unsigned)(l * 8)) ^ swz_row(e))) =
                    make_uint2(u[0], u[1]);
            }
        }
        __syncthreads();

        // Phase 2 (half): accumulate 16 K-steps of h1 @ W2
        {
            const unsigned short* pa = W2F + (size_t)chunk * 16 * 4096 + w * 2 * 512 + l * 8;
            #pragma unroll
            for (int ks = 0; ks < 16; ++ks) {
                f16x8 bfr = *(const f16x8*)(s_h1 + le * 512 +
                              (((unsigned)(ks * 32 + hi * 16)) ^ swz));
                f16x8 a0 = *(const f16x8*)(pa + ks * 4096);
                f16x8 a1 = *(const f16x8*)(pa + ks * 4096 + 512);
                acc0 = __builtin_amdgcn_mfma_f32_32x32x16_f16(a0, bfr, acc0, 0, 0, 0);
                acc1 = __builtin_amdgcn_mfma_f32_32x32x16_f16(a1, bfr, acc1, 0, 0, 0);
            }
        }
        __syncthreads();   // chunk 0: protect s_h1 before overwrite; chunk 1: before h2 write
    }

    // ---- Phase 2 epilogue: h2 = gelu(acc + b2) -> f16 LDS, swizzled ----
    // D[ch][e]: col=l&31 (edge), row=(reg&3)+8*(reg>>2)+4*hi (ch-local)
    #pragma unroll
    for (int t2 = 0; t2 < 2; ++t2) {
        int g = w * 2 + t2;
        #pragma unroll
        for (int q = 0; q < 4; ++q) {
            int ch0 = g * 32 + q * 8 + hi * 4;
            float4 bb = *(const float4*)(b2 + ch0);
            float v0 = (t2 ? acc1[q * 4 + 0] : acc0[q * 4 + 0]) + bb.x;
            float v1 = (t2 ? acc1[q * 4 + 1] : acc0[q * 4 + 1]) + bb.y;
            float v2 = (t2 ? acc1[q * 4 + 2] : acc0[q * 4 + 2]) + bb.z;
            float v3 = (t2 ? acc1[q * 4 + 3] : acc0[q * 4 + 3]) + bb.w;
            unsigned int u0 = f32_to_f16_bits(gelu_fast(v0)) |
                              ((unsigned)f32_to_f16_bits(gelu_fast(v1)) << 16);
            unsigned int u1 = f32_to_f16_bits(gelu_fast(v2)) |
                              ((unsigned)f32_to_f16_bits(gelu_fast(v3)) << 16);
            *(uint2*)(s_h2 + le * 512 + (((unsigned)(ch0 * 2)) ^ swz)) = make_uint2(u0, u1);
        }
    }
    __syncthreads();

    // ---- Phase 3: k = h2 @ W3 + b3 via MFMA (k stays in registers) ----
    f32x16 kc0 = {}, kc1 = {};
    {
        const unsigned short* pa = W3F + w * 2 * 512 + l * 8;
        #pragma unroll
        for (int ks = 0; ks < 16; ++ks) {
            f16x8 bfr = *(const f16x8*)(s_h2 + le * 512 +
                          (((unsigned)(ks * 32 + hi * 16)) ^ swz));
            f16x8 a0 = *(const f16x8*)(pa + ks * 4096);
            f16x8 a1 = *(const f16x8*)(pa + ks * 4096 + 512);
            kc0 = __builtin_amdgcn_mfma_f32_32x32x16_f16(a0, bfr, kc0, 0, 0, 0);
            kc1 = __builtin_amdgcn_mfma_f32_32x32x16_f16(a1, bfr, kc1, 0, 0, 0);
        }
    }

    // ---- Fused phase 4: lane holds 32 channels of edge `le`; dot with f and Wp ----
    {
        int nb = s_nb[le];
        const float* fb0 = latent_embed + (size_t)nb * CCH;
        const float* fb1 = latent_embed + ((size_t)NGRID + nb) * CCH;
        float pm00 = 0.f, pm01 = 0.f, pm02 = 0.f, pm03 = 0.f;
        float pm10 = 0.f, pm11 = 0.f, pm12 = 0.f, pm13 = 0.f;
        #pragma unroll
        for (int t2 = 0; t2 < 2; ++t2) {
            #pragma unroll
            for (int q = 0; q < 4; ++q) {
                int ch0 = (w * 2 + t2) * 32 + q * 8 + hi * 4;
                float4 bb = *(const float4*)(b3 + ch0);
                float kv0 = (t2 ? kc1[q * 4 + 0] : kc0[q * 4 + 0]) + bb.x;
                float kv1 = (t2 ? kc1[q * 4 + 1] : kc0[q * 4 + 1]) + bb.y;
                float kv2 = (t2 ? kc1[q * 4 + 2] : kc0[q * 4 + 2]) + bb.z;
                float kv3 = (t2 ? kc1[q * 4 + 3] : kc0[q * 4 + 3]) + bb.w;
                float4 f0 = *(const float4*)(fb0 + ch0);
                float4 f1 = *(const float4*)(fb1 + ch0);
                float4 wp0 = *(const float4*)(Wp + (ch0 + 0) * 4);
                float4 wp1 = *(const float4*)(Wp + (ch0 + 1) * 4);
                float4 wp2 = *(const float4*)(Wp + (ch0 + 2) * 4);
                float4 wp3 = *(const float4*)(Wp + (ch0 + 3) * 4);
                float t0 = kv0 * f0.x, t1 = kv1 * f0.y, t2v = kv2 * f0.z, t3 = kv3 * f0.w;
                pm00 = fmaf(t0, wp0.x, fmaf(t1, wp1.x, fmaf(t2v, wp2.x, fmaf(t3, wp3.x, pm00))));
                pm01 = fmaf(t0, wp0.y, fmaf(t1, wp1.y, fmaf(t2v, wp2.y, fmaf(t3, wp3.y, pm01))));
                pm02 = fmaf(t0, wp0.z, fmaf(t1, wp1.z, fmaf(t2v, wp2.z, fmaf(t3, wp3.z, pm02))));
                pm03 = fmaf(t0, wp0.w, fmaf(t1, wp1.w, fmaf(t2v, wp2.w, fmaf(t3, wp3.w, pm03))));
                float s0 = kv0 * f1.x, s1 = kv1 * f1.y, s2 = kv2 * f1.z, s3 = kv3 * f1.w;
                pm10 = fmaf(s0, wp0.x, fmaf(s1, wp1.x, fmaf(s2, wp2.x, fmaf(s3, wp3.x, pm10))));
                pm11 = fmaf(s0, wp0.y, fmaf(s1, wp1.y, fmaf(s2, wp2.y, fmaf(s3, wp3.y, pm11))));
                pm12 = fmaf(s0, wp0.z, fmaf(s1, wp1.z, fmaf(s2, wp2.z, fmaf(s3, wp3.z, pm12))));
                pm13 = fmaf(s0, wp0.w, fmaf(s1, wp1.w, fmaf(s2, wp2.w, fmaf(s3, wp3.w, pm13))));
            }
        }
        atomicAdd(&s_pm[le][0], pm00);
        atomicAdd(&s_pm[le][1], pm01);
        atomicAdd(&s_pm[le][2], pm02);
        atomicAdd(&s_pm[le][3], pm03);
        atomicAdd(&s_pm[le][4], pm10);
        atomicAdd(&s_pm[le][5], pm11);
        atomicAdd(&s_pm[le][6], pm12);
        atomicAdd(&s_pm[le][7], pm13);
    }
    __syncthreads();

    // ---- Drain: one global atomic per thread ----
    {
        int el = tid >> 3;
        int v  = tid & 7;
        if (s_valid[el]) {
            int b  = v >> 2;
            int oc = v & 3;
            atomicAdd(&sums[((size_t)b * NOUT + s_oi[el]) * 4 + oc], s_pm[el][v]);
        }
    }
}

__global__ __launch_bounds__(256) void gino_finalize_kernel(
    const float* __restrict__ sums,
    const float* __restrict__ cnt,
    const float* __restrict__ bp,
    float* __restrict__ out)
{
    int idx = blockIdx.x * 256 + threadIdx.x;
    if (idx >= 2 * NOUT * 4) return;
    int oc = idx & 3;
    int i  = (idx >> 2) & (NOUT - 1);
    float c = fmaxf(cnt[i], 1.0f);
    out[idx] = sums[idx] / c + bp[oc];
}

extern "C" void kernel_launch(void* const* d_in, const int* in_sizes, int n_in,
                              void* d_out, int out_size, void* d_ws, size_t ws_size,
                              hipStream_t stream) {
    const float* latent_embed   = (const float*)d_in[0];
    const float* latent_queries = (const float*)d_in[1];
    const float* output_queries = (const float*)d_in[2];
    const int*   nb_index       = (const int*)d_in[3];
    const int*   out_index      = (const int*)d_in[4];
    const float* W1 = (const float*)d_in[5];
    const float* b1 = (const float*)d_in[6];
    const float* W2 = (const float*)d_in[7];
    const float* b2 = (const float*)d_in[8];
    const float* W3 = (const float*)d_in[9];
    const float* b3 = (const float*)d_in[10];
    const float* Wp = (const float*)d_in[11];
    const float* bp = (const float*)d_in[12];

    const int E = in_sizes[3];

    float* sums = (float*)d_ws;                         // 2*16384*4 fp32  (512KB)
    float* cnt  = sums + 2 * NOUT * 4;                  // 16384 fp32      (64KB)
    unsigned short* W2F = (unsigned short*)(cnt + NOUT);// 32*8*64*8 f16   (256KB)
    unsigned short* W3F = W2F + 32 * 8 * 64 * 8;        // 16*8*64*8 f16   (128KB)

    hipMemsetAsync(d_ws, 0, (size_t)(2 * NOUT * 4 + NOUT) * sizeof(float), stream);

    gino_pack_kernel<<<(32 * 8 * 64 + 16 * 8 * 64 + 255) / 256, 256, 0, stream>>>(
        W2, W3, W2F, W3F);

    int nblk = (E + TE - 1) / TE;
    gino_edge_kernel<<<nblk, 256, 0, stream>>>(
        latent_embed, latent_queries, output_queries, nb_index, out_index,
        W1, b1, b2, b3, W2F, W3F, Wp, sums, cnt, E);

    gino_finalize_kernel<<<(2 * NOUT * 4 + 255) / 256, 256, 0, stream>>>(
        sums, cnt, bp, (float*)d_out);
}